// Round 1
// baseline (8023.298 us; speedup 1.0000x reference)
//
#include <hip/hip_runtime.h>

// Problem constants (match reference)
#define DHW   (128*128*128)        // 2^21
#define CDHW  (4*DHW)              // 2^23
#define NTOT  (2*CDHW)             // 2^24 = 16,777,216
#define NCLS  4
#define NB    2

// Kernel A: softmax over C=4, subtract one-hot(target), square -> buf0.
// Thread j covers one (b, d, h, w) site, writes 4 class outputs.
// Thread 0 also zero-inits the double accumulator (ws is poisoned 0xAA).
__global__ __launch_bounds__(256) void softmax_sq_kernel(
    const float* __restrict__ in, const int* __restrict__ tgt,
    float* __restrict__ out, double* __restrict__ acc)
{
    int j = blockIdx.x * 256 + threadIdx.x;       // [0, NB*DHW)
    if (j == 0) *acc = 0.0;

    int b = j >> 21;                // DHW = 2^21
    int s = j & (DHW - 1);
    const float* p = in + (size_t)b * CDHW + s;

    float a0 = p[0];
    float a1 = p[DHW];
    float a2 = p[2 * DHW];
    float a3 = p[3 * DHW];

    float m  = fmaxf(fmaxf(a0, a1), fmaxf(a2, a3));
    float e0 = expf(a0 - m);
    float e1 = expf(a1 - m);
    float e2 = expf(a2 - m);
    float e3 = expf(a3 - m);
    float inv = 1.0f / (e0 + e1 + e2 + e3);

    int t = tgt[j];

    float* q = out + (size_t)b * CDHW + s;
    float d0 = e0 * inv - (t == 0 ? 1.0f : 0.0f);
    float d1 = e1 * inv - (t == 1 ? 1.0f : 0.0f);
    float d2 = e2 * inv - (t == 2 ? 1.0f : 0.0f);
    float d3 = e3 * inv - (t == 3 ? 1.0f : 0.0f);
    q[0]       = d0 * d0;
    q[DHW]     = d1 * d1;
    q[2 * DHW] = d2 * d2;
    q[3 * DHW] = d3 * d3;
}

// Kernel B: 7-point cross stencil * wk + bias[c], ReLU -> dst.
// Also accumulates sum(dst) * weight[b,c] * coef into *acc (one f64 atomic/block).
// Block = 256 consecutive linear indices -> always within one (b,c) slab
// (slab = 2^21 elements, divisible by 256).
__global__ __launch_bounds__(256) void erode_kernel(
    const float* __restrict__ src, float* __restrict__ dst,
    const float* __restrict__ kern, const float* __restrict__ bias,
    const float* __restrict__ weight, float coef, double* __restrict__ acc)
{
    int idx = blockIdx.x * 256 + threadIdx.x;     // [0, NTOT)
    int x  = idx & 127;
    int y  = (idx >> 7) & 127;
    int z  = (idx >> 14) & 127;
    int bc = idx >> 21;                           // b*4 + c in [0,8)

    float wk = kern[13];                          // center tap; all 7 taps equal
    float bs = bias[bc & 3];

    float s7 = src[idx];
    s7 += (x > 0)   ? src[idx - 1]     : 0.0f;
    s7 += (x < 127) ? src[idx + 1]     : 0.0f;
    s7 += (y > 0)   ? src[idx - 128]   : 0.0f;
    s7 += (y < 127) ? src[idx + 128]   : 0.0f;
    s7 += (z > 0)   ? src[idx - 16384] : 0.0f;
    s7 += (z < 127) ? src[idx + 16384] : 0.0f;

    float v = fmaxf(s7 * wk + bs, 0.0f);
    dst[idx] = v;

    // block reduction of v
    float part = v;
    #pragma unroll
    for (int off = 32; off > 0; off >>= 1)
        part += __shfl_down(part, off, 64);

    __shared__ float wsum[4];
    int lane = threadIdx.x & 63;
    int wid  = threadIdx.x >> 6;
    if (lane == 0) wsum[wid] = part;
    __syncthreads();
    if (threadIdx.x == 0) {
        float tot = wsum[0] + wsum[1] + wsum[2] + wsum[3];
        double sc = (double)weight[bc] * (double)coef;   // weight is (B,C) row-major
        atomicAdd(acc, (double)tot * sc);
    }
}

__global__ void finalize_kernel(const double* __restrict__ acc, float* __restrict__ out)
{
    out[0] = (float)(acc[0] / (double)NTOT);
}

extern "C" void kernel_launch(void* const* d_in, const int* in_sizes, int n_in,
                              void* d_out, int out_size, void* d_ws, size_t ws_size,
                              hipStream_t stream) {
    const float* in     = (const float*)d_in[0];
    const int*   tgt    = (const int*)d_in[1];
    const float* weight = (const float*)d_in[2];
    const float* kern   = (const float*)d_in[3];
    const float* bias   = (const float*)d_in[4];
    float* out = (float*)d_out;

    char* ws = (char*)d_ws;
    float*  buf0 = (float*)ws;
    float*  buf1 = (float*)(ws + (size_t)NTOT * sizeof(float));
    double* acc  = (double*)(ws + (size_t)NTOT * 2 * sizeof(float));

    // 1) softmax + one-hot + square (also zeroes acc)
    softmax_sq_kernel<<<(NB * DHW) / 256, 256, 0, stream>>>(in, tgt, buf0, acc);

    // 2) 10 erosion steps, ping-pong, fused weighted-sum accumulation
    float* cur = buf0;
    float* nxt = buf1;
    for (int k = 0; k < 10; ++k) {
        float coef = (float)((k + 1) * (k + 1));
        erode_kernel<<<NTOT / 256, 256, 0, stream>>>(cur, nxt, kern, bias, weight, coef, acc);
        float* t = cur; cur = nxt; nxt = t;
    }

    // 3) mean
    finalize_kernel<<<1, 1, 0, stream>>>(acc, out);
}

// Round 3
// 433.064 us; speedup vs baseline: 18.5268x; 18.5268x over previous
//
#include <hip/hip_runtime.h>

// Problem constants (match reference)
#define DHW   (128*128*128)        // 2^21
#define CDHW  (4*DHW)              // 2^23
#define NTOT  (2*CDHW)             // 2^24 = 16,777,216
#define NSITE (2*DHW)              // B*DHW = 2^22 sites
#define NACC  1024                 // spread accumulator slots

// Kernel A: softmax over C=4, subtract one-hot(target), square -> buf0.
// Vectorized: each thread handles 4 consecutive sites (float4 per class plane).
// Also zero-inits the spread accumulator array (ws is poisoned 0xAA).
__global__ __launch_bounds__(256) void softmax_sq_kernel(
    const float* __restrict__ in, const int* __restrict__ tgt,
    float* __restrict__ out, double* __restrict__ accs)
{
    int j4 = blockIdx.x * 256 + threadIdx.x;      // [0, NSITE/4)
    if (j4 < NACC) accs[j4] = 0.0;

    int base = j4 << 2;                           // site index [0, NSITE)
    int b = base >> 21;                           // DHW = 2^21
    int s = base & (DHW - 1);
    const float* p = in + (size_t)b * CDHW + s;

    float4 a0 = *(const float4*)(p);
    float4 a1 = *(const float4*)(p + DHW);
    float4 a2 = *(const float4*)(p + 2 * DHW);
    float4 a3 = *(const float4*)(p + 3 * DHW);
    int4   t  = *(const int4*)(tgt + base);

    float4 o0, o1, o2, o3;
    #define SOFTMAX1(K)                                                        \
    {                                                                          \
        float v0 = a0.K, v1 = a1.K, v2 = a2.K, v3 = a3.K;                      \
        float m  = fmaxf(fmaxf(v0, v1), fmaxf(v2, v3));                        \
        float e0 = expf(v0 - m), e1 = expf(v1 - m);                            \
        float e2 = expf(v2 - m), e3 = expf(v3 - m);                            \
        float inv = 1.0f / (e0 + e1 + e2 + e3);                                \
        int   tv = t.K;                                                        \
        float d0 = e0 * inv - (tv == 0 ? 1.0f : 0.0f);                         \
        float d1 = e1 * inv - (tv == 1 ? 1.0f : 0.0f);                         \
        float d2 = e2 * inv - (tv == 2 ? 1.0f : 0.0f);                         \
        float d3 = e3 * inv - (tv == 3 ? 1.0f : 0.0f);                         \
        o0.K = d0 * d0; o1.K = d1 * d1; o2.K = d2 * d2; o3.K = d3 * d3;        \
    }
    SOFTMAX1(x) SOFTMAX1(y) SOFTMAX1(z) SOFTMAX1(w)
    #undef SOFTMAX1

    float* q = out + (size_t)b * CDHW + s;
    *(float4*)(q)           = o0;
    *(float4*)(q + DHW)     = o1;
    *(float4*)(q + 2 * DHW) = o2;
    *(float4*)(q + 3 * DHW) = o3;
}

// Kernel B: 7-point cross stencil * wk + bias[c], ReLU -> dst. float4 per thread.
// Accumulates sum(dst)*weight[b,c]*coef into accs[block & (NACC-1)].
__global__ __launch_bounds__(256) void erode_kernel(
    const float4* __restrict__ src4, float4* __restrict__ dst4,
    const float* __restrict__ kern, const float* __restrict__ bias,
    const float* __restrict__ weight, float coef, double* __restrict__ accs)
{
    int i4 = blockIdx.x * 256 + threadIdx.x;      // [0, NTOT/4)
    int e  = i4 << 2;                             // element index
    int x4 = i4 & 31;                             // row = 32 float4s
    int y  = (e >> 7) & 127;
    int z  = (e >> 14) & 127;
    int bc = e >> 21;                             // b*4 + c in [0,8)

    const float* src = (const float*)src4;
    float4 c = src4[i4];
    float lf = (x4 > 0)  ? src[e - 1] : 0.0f;     // element left of c.x
    float rt = (x4 < 31) ? src[e + 4] : 0.0f;     // element right of c.w

    float4 s;
    s.x = c.x + lf  + c.y;
    s.y = c.y + c.x + c.z;
    s.z = c.z + c.y + c.w;
    s.w = c.w + c.z + rt;

    if (y > 0)   { float4 t = src4[i4 - 32];   s.x += t.x; s.y += t.y; s.z += t.z; s.w += t.w; }
    if (y < 127) { float4 t = src4[i4 + 32];   s.x += t.x; s.y += t.y; s.z += t.z; s.w += t.w; }
    if (z > 0)   { float4 t = src4[i4 - 4096]; s.x += t.x; s.y += t.y; s.z += t.z; s.w += t.w; }
    if (z < 127) { float4 t = src4[i4 + 4096]; s.x += t.x; s.y += t.y; s.z += t.z; s.w += t.w; }

    float wk = kern[13];                          // all 7 taps equal
    float bs = bias[bc & 3];
    float4 v;
    v.x = fmaxf(s.x * wk + bs, 0.0f);
    v.y = fmaxf(s.y * wk + bs, 0.0f);
    v.z = fmaxf(s.z * wk + bs, 0.0f);
    v.w = fmaxf(s.w * wk + bs, 0.0f);
    dst4[i4] = v;

    // block reduction of v
    float part = v.x + v.y + v.z + v.w;
    #pragma unroll
    for (int off = 32; off > 0; off >>= 1)
        part += __shfl_down(part, off, 64);

    __shared__ float wsum[4];
    int lane = threadIdx.x & 63;
    int wid  = threadIdx.x >> 6;
    if (lane == 0) wsum[wid] = part;
    __syncthreads();
    if (threadIdx.x == 0) {
        float tot = wsum[0] + wsum[1] + wsum[2] + wsum[3];
        double sc = (double)weight[bc] * (double)coef;   // weight is (B,C) row-major
        atomicAdd(&accs[blockIdx.x & (NACC - 1)], (double)tot * sc);
    }
}

// Reduce the NACC spread accumulators -> scalar mean.
__global__ __launch_bounds__(1024) void finalize_kernel(
    const double* __restrict__ accs, float* __restrict__ out)
{
    __shared__ double wsum[16];
    double v = accs[threadIdx.x];
    #pragma unroll
    for (int off = 32; off > 0; off >>= 1)
        v += __shfl_down(v, off, 64);
    int lane = threadIdx.x & 63;
    int wid  = threadIdx.x >> 6;
    if (lane == 0) wsum[wid] = v;
    __syncthreads();
    if (threadIdx.x == 0) {
        double tot = 0.0;
        #pragma unroll
        for (int i = 0; i < 16; ++i) tot += wsum[i];
        out[0] = (float)(tot / (double)NTOT);
    }
}

extern "C" void kernel_launch(void* const* d_in, const int* in_sizes, int n_in,
                              void* d_out, int out_size, void* d_ws, size_t ws_size,
                              hipStream_t stream) {
    const float* in     = (const float*)d_in[0];
    const int*   tgt    = (const int*)d_in[1];
    const float* weight = (const float*)d_in[2];
    const float* kern   = (const float*)d_in[3];
    const float* bias   = (const float*)d_in[4];
    float* out = (float*)d_out;

    char* ws = (char*)d_ws;
    float*  buf0 = (float*)ws;
    float*  buf1 = (float*)(ws + (size_t)NTOT * sizeof(float));
    double* accs = (double*)(ws + (size_t)NTOT * 2 * sizeof(float));

    // 1) softmax + one-hot + square (also zeroes accs)
    softmax_sq_kernel<<<(NSITE / 4) / 256, 256, 0, stream>>>(in, tgt, buf0, accs);

    // 2) 10 erosion steps, ping-pong, fused weighted partial-sum accumulation
    float* cur = buf0;
    float* nxt = buf1;
    for (int k = 0; k < 10; ++k) {
        float coef = (float)((k + 1) * (k + 1));
        erode_kernel<<<(NTOT / 4) / 256, 256, 0, stream>>>(
            (const float4*)cur, (float4*)nxt, kern, bias, weight, coef, accs);
        float* t = cur; cur = nxt; nxt = t;
    }

    // 3) reduce + mean
    finalize_kernel<<<1, 1024, 0, stream>>>(accs, out);
}